// Round 8
// baseline (603.422 us; speedup 1.0000x reference)
//
#include <hip/hip_runtime.h>
#include <hip/hip_bf16.h>
#include <stdint.h>

// Problem sizes (fixed by the reference)
#define IN_F  4096
#define OUT_F 4096
#define NROWS 16384
#define NT    (IN_F / 64)   // 64 K-tiles of BK=64

typedef unsigned short u16;
typedef unsigned int u32;
typedef unsigned long long u64;
typedef __bf16 bf16x8 __attribute__((ext_vector_type(8)));
typedef float  f32x4  __attribute__((ext_vector_type(4)));
typedef u16    u16x8  __attribute__((ext_vector_type(8)));

#define BAR()   asm volatile("s_barrier" ::: "memory")
#define LGKM0() asm volatile("s_waitcnt lgkmcnt(0)" ::: "memory")
#define VM4()   asm volatile("s_waitcnt vmcnt(4)" ::: "memory")
#define VM0()   asm volatile("s_waitcnt vmcnt(0)" ::: "memory")

// fp32 -> bf16, round-to-nearest-even (finite inputs only)
__device__ __forceinline__ u16 f2bf(float x) {
    union { float f; uint32_t u; } c; c.f = x;
    uint32_t u = c.u;
    return (u16)((u + 0x7FFFu + ((u >> 16) & 1u)) >> 16);
}

// async global->LDS, 16B per lane. LDS dest = wave-uniform base + lane*16.
__device__ __forceinline__ void gload_lds16(const void* g, void* l) {
    __builtin_amdgcn_global_load_lds(
        (const __attribute__((address_space(1))) void*)g,
        (__attribute__((address_space(3))) void*)l, 16, 0, 0);
}

__device__ __forceinline__ u16 sgn_bf16(float v) {
    return v > 0.f ? 0x3F80 : (v < 0.f ? 0xBF80 : 0);
}

// --- Prep 1 (fast path): per-row alpha = mean(|W|) AND bit-packed signs,
// TRANSPOSED layout: Wbits[kword][row] -> one K-tile's bits for 256 rows are
// a contiguous 2KB burst. Bitmap = 2MB, L2-resident (r4: FETCH 1.16GB->102MB).
__global__ void prep_wbits_kernel(const float* __restrict__ W,
                                  float* __restrict__ alpha,
                                  u64* __restrict__ Wbits) {
    const int row = blockIdx.x;                       // 0..OUT_F-1
    const int wave = threadIdx.x >> 6, lane = threadIdx.x & 63;
    const float* wr = W + (size_t)row * IN_F;
    float s = 0.f;
#pragma unroll 4
    for (int it = 0; it < 16; ++it) {
        const int kword = it * 4 + wave;              // 64 words per row
        float v = __builtin_nontemporal_load(wr + kword * 64 + lane);
        s += fabsf(v);
        u64 m = __ballot(v > 0.f);                    // 64-bit wave mask
        if (lane == 0) Wbits[(size_t)kword * OUT_F + row] = m;   // transposed
    }
    for (int off = 32; off > 0; off >>= 1) s += __shfl_down(s, off);
    __shared__ float red[4];
    if (lane == 0) red[wave] = s;
    __syncthreads();
    if (threadIdx.x == 0)
        alpha[row] = (red[0] + red[1] + red[2] + red[3]) * (1.0f / IN_F);
}

// --- Prep 2: x fp32 -> bf16 (RNE), chunk-swizzled for T2 (c8 ^= row&7) ---
__global__ void convx_kernel(const float* __restrict__ X, u16* __restrict__ O,
                             int swz) {
    const size_t idx = (size_t)blockIdx.x * 256 + threadIdx.x; // 16B out chunk
    const int row = (int)(idx >> 9);                 // 512 chunks per row
    const int q = (int)idx & 511;
    const int g = q >> 3, c8 = q & 7;
    const int c8s = swz ? (c8 ^ (row & 7)) : c8;
    const f32x4* src = reinterpret_cast<const f32x4*>(
        X + (size_t)row * IN_F + g * 64 + c8s * 8);
    f32x4 a = __builtin_nontemporal_load(src);
    f32x4 b = __builtin_nontemporal_load(src + 1);
    u16x8 r;
    r[0] = f2bf(a[0]); r[1] = f2bf(a[1]); r[2] = f2bf(a[2]); r[3] = f2bf(a[3]);
    r[4] = f2bf(b[0]); r[5] = f2bf(b[1]); r[6] = f2bf(b[2]); r[7] = f2bf(b[3]);
    reinterpret_cast<u16x8*>(O)[idx] = r;
}

// ============================================================================
// 256x256 GEMM, bit-B round 7 (resubmit; r7 was a compile typo in fallback):
// DEEP A-PIPELINE (T4 counted vmcnt).
// r6 verified: LDS-cooperative B expansion, no spill, FETCH 109MB, MfmaUtil
// 42.9% @ 543us. Remaining stall = shallow A prefetch: A(t+1) issued phi1/2
// and drained by VM0 at the SAME tile's boundary (~2 phases in flight).
// Change: A triple-buffered (3x32KB) + B double (2x32KB) = 160KB LDS (full
// CU budget). Stage A(t+2) at phi2/phi3 (6 phases before use); boundary is
// counted VM4, never 0 in steady state.
// vmcnt ledger (per-wave issue order): tile t issues bits(t+2)@phi0,
// A(t+2)lo x2 @phi2, A(t+2)hi x2 @phi3. Steady-state queue at t's boundary:
// [A(t+1)x4 (from t-1), bits(t+2), A(t+2)x4] = 9 -> VM4 drains A(t+1)x4 +
// bits(t+2) (both consumed during t+1), leaves A(t+2)x4 riding the barrier.
// Prologue: [bits(0),A(0)x4,bits(1),A(1)x4]=10 -> VM4 drains 6, leaves A(1).
// Tail: t>=NT-2 -> VM0 (A(NT-1) must complete; VM4 would no-op).
// Expansion writes B(t+1) into Blds[(t+1)&1] at phi1/phi2 (under the matrix
// pipe); own-wave LGKM0 at boundary + BAR makes them visible (as r6).
// A(t+2) overwrites the buffer that held A(t-1) (last read 4+ barriers ago).
// ============================================================================
__global__ __launch_bounds__(512, 2) void gemm8_kernel(
    const u16* __restrict__ Xbf, const u64* __restrict__ Wbits,
    const float* __restrict__ alpha, const float* __restrict__ bias,
    float* __restrict__ Y) {
    __shared__ u16 Alds[3][16384];   // 96KB: A triple buffer [256 rows][64 k]
    __shared__ u16 Blds[2][16384];   // 64KB: B double buffer

    const int tid  = threadIdx.x;
    const int lane = tid & 63, wave = tid >> 6;
    const int wm = wave >> 2, wn = wave & 3;      // 2(M) x 4(N) waves
    const int lrow = lane & 15;

    const int wg = blockIdx.x;
    const int i  = wg >> 3;                       // 0..127 within XCD
    const int m0 = (((wg & 7) << 3) | (i >> 4)) << 8;   // xcd*8 + m_local
    const int n0 = (i & 15) << 8;

    // T2 swizzled ds_read k-offsets (u16 units)
    const int q0 = ((lane >> 4) << 3) ^ ((lrow & 7) << 3);
    const int q1 = q0 ^ 32;

    // B-expansion assignment: thread owns 32 bits = row erow, k-half ehalf
    const int erow = tid >> 1, ehalf = tid & 1;
    const u32* Wb32 = reinterpret_cast<const u32*>(Wbits);

    f32x4 acc[8][4];
#pragma unroll
    for (int a = 0; a < 8; ++a)
#pragma unroll
        for (int b = 0; b < 4; ++b) acc[a][b] = (f32x4){0.f, 0.f, 0.f, 0.f};

    // stage one 128-row half of A K-tile th (2 gload_lds16 / thread)
    auto stageA = [&](int th, int half, u16* buf) {
        if (th >= NT) return;
#pragma unroll
        for (int t2 = 0; t2 < 2; ++t2) {
            const int c = half * 1024 + t2 * 512 + tid;   // 16B chunk idx
            const int row = c >> 3, c8 = c & 7;
            gload_lds16(Xbf + (size_t)(m0 + row) * IN_F + th * 64 + c8 * 8,
                        buf + c * 8);
        }
    };

    // expand 2 of this thread's 4 chunks (j = jlo, jlo+1) into Blds[dstbuf].
    // bit=1 -> +1 (0x3F80), bit=0 -> -1 (0xBF80); T2 store swizzle k8^(row&7).
    auto expandB = [&](unsigned b, int dstbuf, int jlo) {
        unsigned nb = ~b;
        u16* base = &Blds[dstbuf][erow * 64];
#pragma unroll
        for (int j = 0; j < 2; ++j) {
            const int jj = jlo + j;
            const int k8 = 4 * ehalf + jj;
            union { unsigned u[4]; u16x8 v; } r;
#pragma unroll
            for (int e = 0; e < 4; ++e) {
                unsigned s = nb >> (jj * 8 + 2 * e);
                r.u[e] = 0x3F803F80u | ((s & 1u) << 15) | ((s & 2u) << 30);
            }
            *reinterpret_cast<u16x8*>(base + ((k8 ^ (erow & 7)) << 3)) = r.v;
        }
    };

    // rotating A-buffer pointers: pa0 = A(t), pa1 = A(t+1), pa2 = stage target
    u16* pa0 = &Alds[0][0];
    u16* pa1 = &Alds[1][0];
    u16* pa2 = &Alds[2][0];

    // ---- prologue ----
    unsigned b0 = Wb32[(size_t)(n0 + erow) * 2 + ehalf];              // bits(0)
    stageA(0, 0, pa0); stageA(0, 1, pa0);
    unsigned bits_cur = Wb32[(size_t)8192 + (n0 + erow) * 2 + ehalf]; // bits(1)
    stageA(1, 0, pa1); stageA(1, 1, pa1);
    unsigned bits_nxt = 0;
    VM4();   // queue [bits0,A0x4,bits1,A1x4]=10 -> drains 6, leaves A(1)x4
    expandB(b0, 0, 0); expandB(b0, 0, 2);
    LGKM0(); BAR();

    for (int t = 0; t < NT; ++t) {
        const u16* Ar = pa0 + wm * 8192 + lrow * 64;
        const u16* Br = &Blds[t & 1][0] + wn * 4096 + lrow * 64;
        bf16x8 a0[4][2], a1[4][2], bfr[4][2];

        // --- phi0: ds_read a0 + B frags; load bits(t+2); MFMA mh0 x np0 ---
#pragma unroll
        for (int mm = 0; mm < 4; ++mm) {
            a0[mm][0] = *reinterpret_cast<const bf16x8*>(Ar + mm * 1024 + q0);
            a0[mm][1] = *reinterpret_cast<const bf16x8*>(Ar + mm * 1024 + q1);
        }
#pragma unroll
        for (int nf = 0; nf < 4; ++nf) {
            bfr[nf][0] = *reinterpret_cast<const bf16x8*>(Br + nf * 1024 + q0);
            bfr[nf][1] = *reinterpret_cast<const bf16x8*>(Br + nf * 1024 + q1);
        }
        if (t + 2 < NT)
            bits_nxt = Wb32[(size_t)(t + 2) * 8192 + (n0 + erow) * 2 + ehalf];
        BAR(); LGKM0();
        __builtin_amdgcn_s_setprio(1);
#pragma unroll
        for (int mm = 0; mm < 4; ++mm)
#pragma unroll
            for (int nn = 0; nn < 2; ++nn) {
                acc[mm][nn] = __builtin_amdgcn_mfma_f32_16x16x32_bf16(a0[mm][0], bfr[nn][0], acc[mm][nn], 0, 0, 0);
                acc[mm][nn] = __builtin_amdgcn_mfma_f32_16x16x32_bf16(a0[mm][1], bfr[nn][1], acc[mm][nn], 0, 0, 0);
            }
        __builtin_amdgcn_s_setprio(0);
        BAR();

        // --- phi1: ds_read a1; MFMA mh0 x np1; expand B(t+1) half0 ---
#pragma unroll
        for (int mm = 0; mm < 4; ++mm) {
            a1[mm][0] = *reinterpret_cast<const bf16x8*>(Ar + (4 + mm) * 1024 + q0);
            a1[mm][1] = *reinterpret_cast<const bf16x8*>(Ar + (4 + mm) * 1024 + q1);
        }
        BAR();
        __builtin_amdgcn_s_setprio(1);
#pragma unroll
        for (int mm = 0; mm < 4; ++mm)
#pragma unroll
            for (int nn = 0; nn < 2; ++nn) {
                acc[mm][2 + nn] = __builtin_amdgcn_mfma_f32_16x16x32_bf16(a0[mm][0], bfr[2 + nn][0], acc[mm][2 + nn], 0, 0, 0);
                acc[mm][2 + nn] = __builtin_amdgcn_mfma_f32_16x16x32_bf16(a0[mm][1], bfr[2 + nn][1], acc[mm][2 + nn], 0, 0, 0);
            }
        __builtin_amdgcn_s_setprio(0);
        if (t + 1 < NT) expandB(bits_cur, (t + 1) & 1, 0);  // under matrix pipe
        BAR();

        // --- phi2: stage A(t+2) lo; drain a1; MFMA mh1 x np0; expand half1 ---
        stageA(t + 2, 0, pa2);
        BAR(); LGKM0();
        __builtin_amdgcn_s_setprio(1);
#pragma unroll
        for (int mm = 0; mm < 4; ++mm)
#pragma unroll
            for (int nn = 0; nn < 2; ++nn) {
                acc[4 + mm][nn] = __builtin_amdgcn_mfma_f32_16x16x32_bf16(a1[mm][0], bfr[nn][0], acc[4 + mm][nn], 0, 0, 0);
                acc[4 + mm][nn] = __builtin_amdgcn_mfma_f32_16x16x32_bf16(a1[mm][1], bfr[nn][1], acc[4 + mm][nn], 0, 0, 0);
            }
        __builtin_amdgcn_s_setprio(0);
        if (t + 1 < NT) expandB(bits_cur, (t + 1) & 1, 2);
        BAR();

        // --- phi3: stage A(t+2) hi; MFMA mh1 x np1; counted boundary ---
        stageA(t + 2, 1, pa2);
        __builtin_amdgcn_s_setprio(1);
#pragma unroll
        for (int mm = 0; mm < 4; ++mm)
#pragma unroll
            for (int nn = 0; nn < 2; ++nn) {
                acc[4 + mm][2 + nn] = __builtin_amdgcn_mfma_f32_16x16x32_bf16(a1[mm][0], bfr[2 + nn][0], acc[4 + mm][2 + nn], 0, 0, 0);
                acc[4 + mm][2 + nn] = __builtin_amdgcn_mfma_f32_16x16x32_bf16(a1[mm][1], bfr[2 + nn][1], acc[4 + mm][2 + nn], 0, 0, 0);
            }
        __builtin_amdgcn_s_setprio(0);
        if (t >= NT - 2) { VM0(); } else { VM4(); }
        LGKM0(); BAR();

        bits_cur = bits_nxt;
        u16* tp = pa0; pa0 = pa1; pa1 = pa2; pa2 = tp;
    }

    // epilogue: y = acc*alpha[col] + bias[col]; C/D: col=lane&15, row=(lane>>4)*4+r
#pragma unroll
    for (int nf = 0; nf < 4; ++nf) {
        const int col = n0 + wn * 64 + nf * 16 + lrow;
        const float al = alpha[col], bi = bias[col];
#pragma unroll
        for (int mf = 0; mf < 8; ++mf) {
            const int rbase = m0 + wm * 128 + mf * 16 + ((lane >> 4) << 2);
#pragma unroll
            for (int r = 0; r < 4; ++r)
                __builtin_nontemporal_store(acc[mf][nf][r] * al + bi,
                    &Y[(size_t)(rbase + r) * OUT_F + col]);
        }
    }
}

// ============================================================================
// Fallback (small workspace): round-1 128x128 kernel, A reg-staged from fp32,
// bf16 Wsign unswizzled. Verified correct in round 1.
// ============================================================================
__global__ void prep_w_kernel(const float* __restrict__ W,
                              float* __restrict__ alpha,
                              u16* __restrict__ S) {
    const int row = blockIdx.x;
    const float* wr = W + (size_t)row * IN_F;
    float s = 0.f;
    for (int c = threadIdx.x; c < 512; c += 256) {
        const f32x4* src = reinterpret_cast<const f32x4*>(wr + c * 8);
        f32x4 v0 = __builtin_nontemporal_load(src);
        f32x4 v1 = __builtin_nontemporal_load(src + 1);
        s += fabsf(v0[0]) + fabsf(v0[1]) + fabsf(v0[2]) + fabsf(v0[3])
           + fabsf(v1[0]) + fabsf(v1[1]) + fabsf(v1[2]) + fabsf(v1[3]);
        u16x8 r;
        r[0] = sgn_bf16(v0[0]); r[1] = sgn_bf16(v0[1]);
        r[2] = sgn_bf16(v0[2]); r[3] = sgn_bf16(v0[3]);
        r[4] = sgn_bf16(v1[0]); r[5] = sgn_bf16(v1[1]);
        r[6] = sgn_bf16(v1[2]); r[7] = sgn_bf16(v1[3]);
        *reinterpret_cast<u16x8*>(S + (size_t)row * IN_F + c * 8) = r;
    }
    for (int off = 32; off > 0; off >>= 1) s += __shfl_down(s, off);
    __shared__ float red[4];
    const int wave = threadIdx.x >> 6, lane = threadIdx.x & 63;
    if (lane == 0) red[wave] = s;
    __syncthreads();
    if (threadIdx.x == 0)
        alpha[row] = (red[0] + red[1] + red[2] + red[3]) * (1.0f / IN_F);
}

__global__ __launch_bounds__(256) void gemm_fallback(
    const float* __restrict__ X, const u16* __restrict__ Wsign,
    const float* __restrict__ alpha, const float* __restrict__ bias,
    float* __restrict__ Y) {
    __shared__ u16 Axl[128 * 64];
    __shared__ u16 Bxl[128 * 64];

    const int tid = threadIdx.x;
    const int n0 = blockIdx.x * 128;
    const int m0 = blockIdx.y * 128;
    const int wave = tid >> 6, lane = tid & 63;
    const int wm = wave >> 1, wn = wave & 1;
    const int lrow = lane & 15;
    const int lk8 = (lane >> 4) * 8;

    f32x4 acc[4][4];
#pragma unroll
    for (int a = 0; a < 4; ++a)
#pragma unroll
        for (int b = 0; b < 4; ++b) acc[a][b] = (f32x4){0.f, 0.f, 0.f, 0.f};

    for (int kt = 0; kt < IN_F; kt += 64) {
#pragma unroll
        for (int j = 0; j < 4; ++j) {
            const int idx = j * 256 + tid;
            const int row = idx >> 3, c8 = idx & 7;
            gload_lds16(Wsign + (size_t)(n0 + row) * IN_F + kt + c8 * 8,
                        &Bxl[idx * 8]);
        }
#pragma unroll
        for (int j = 0; j < 4; ++j) {
            const int idx = j * 256 + tid;
            const int row = idx >> 3, c8 = idx & 7;
            const float* src = X + (size_t)(m0 + row) * IN_F + kt + c8 * 8;
            float4 v0 = *reinterpret_cast<const float4*>(src);
            float4 v1 = *reinterpret_cast<const float4*>(src + 4);
            u16x8 r;
            r[0] = f2bf(v0.x); r[1] = f2bf(v0.y); r[2] = f2bf(v0.z); r[3] = f2bf(v0.w);
            r[4] = f2bf(v1.x); r[5] = f2bf(v1.y); r[6] = f2bf(v1.z); r[7] = f2bf(v1.w);
            *reinterpret_cast<u16x8*>(&Axl[idx * 8]) = r;
        }
        __syncthreads();
#pragma unroll
        for (int kk = 0; kk < 2; ++kk) {
            bf16x8 af[4], bfv[4];
#pragma unroll
            for (int mf = 0; mf < 4; ++mf)
                af[mf] = *reinterpret_cast<const bf16x8*>(
                    &Axl[(wm * 64 + mf * 16 + lrow) * 64 + kk * 32 + lk8]);
#pragma unroll
            for (int nf = 0; nf < 4; ++nf)
                bfv[nf] = *reinterpret_cast<const bf16x8*>(
                    &Bxl[(wn * 64 + nf * 16 + lrow) * 64 + kk * 32 + lk8]);
#pragma unroll
            for (int mf = 0; mf < 4; ++mf)
#pragma unroll
                for (int nf = 0; nf < 4; ++nf)
                    acc[mf][nf] = __builtin_amdgcn_mfma_f32_16x16x32_bf16(
                        af[mf], bfv[nf], acc[mf][nf], 0, 0, 0);
        }
        __syncthreads();
    }
#pragma unroll
    for (int nf = 0; nf < 4; ++nf) {
        const int col = n0 + wn * 64 + nf * 16 + lrow;
        const float al = alpha[col], bi = bias[col];
#pragma unroll
        for (int mf = 0; mf < 4; ++mf) {
            const int rbase = m0 + wm * 64 + mf * 16 + (lane >> 4) * 4;
#pragma unroll
            for (int r = 0; r < 4; ++r)
                __builtin_nontemporal_store(acc[mf][nf][r] * al + bi,
                    &Y[(size_t)(rbase + r) * OUT_F + col]);
        }
    }
}

extern "C" void kernel_launch(void* const* d_in, const int* in_sizes, int n_in,
                              void* d_out, int out_size, void* d_ws, size_t ws_size,
                              hipStream_t stream) {
    const float* X    = (const float*)d_in[0];
    const float* W    = (const float*)d_in[1];
    const float* bias = (const float*)d_in[2];
    float* Y = (float*)d_out;

    char* ws = (char*)d_ws;
    float* alpha = (float*)ws;                               // 16 KB
    const size_t WBITS_OFF = 16384;
    const size_t XBF_OFF   = WBITS_OFF + (size_t)OUT_F * (IN_F / 8); // +2 MB
    const size_t need_fast = XBF_OFF + (size_t)NROWS * IN_F * 2;     // +128 MB

    if (ws_size >= need_fast) {
        u64* Wbits = (u64*)(ws + WBITS_OFF);
        u16* Xbf   = (u16*)(ws + XBF_OFF);
        prep_wbits_kernel<<<OUT_F, 256, 0, stream>>>(W, alpha, Wbits);
        convx_kernel<<<(size_t)NROWS * IN_F / 8 / 256, 256, 0, stream>>>(X, Xbf, 1);
        gemm8_kernel<<<dim3(1024), 512, 0, stream>>>(Xbf, Wbits, alpha, bias, Y);
    } else {
        u16* Wsign = (u16*)(ws + 16384);
        prep_w_kernel<<<OUT_F, 256, 0, stream>>>(W, alpha, Wsign);
        dim3 grid(OUT_F / 128, NROWS / 128);
        gemm_fallback<<<grid, 256, 0, stream>>>(X, Wsign, alpha, bias, Y);
    }
}

// Round 9
// 523.517 us; speedup vs baseline: 1.1526x; 1.1526x over previous
//
#include <hip/hip_runtime.h>
#include <hip/hip_bf16.h>
#include <stdint.h>

// Problem sizes (fixed by the reference)
#define IN_F  4096
#define OUT_F 4096
#define NROWS 16384
#define NT    (IN_F / 64)   // 64 K-tiles of BK=64

typedef unsigned short u16;
typedef unsigned int u32;
typedef unsigned long long u64;
typedef __bf16 bf16x8 __attribute__((ext_vector_type(8)));
typedef float  f32x4  __attribute__((ext_vector_type(4)));
typedef u16    u16x8  __attribute__((ext_vector_type(8)));

#define BAR()   asm volatile("s_barrier" ::: "memory")
#define LGKM0() asm volatile("s_waitcnt lgkmcnt(0)" ::: "memory")
#define VM4()   asm volatile("s_waitcnt vmcnt(4)" ::: "memory")
#define VM0()   asm volatile("s_waitcnt vmcnt(0)" ::: "memory")

// fp32 -> bf16, round-to-nearest-even (finite inputs only)
__device__ __forceinline__ u16 f2bf(float x) {
    union { float f; uint32_t u; } c; c.f = x;
    uint32_t u = c.u;
    return (u16)((u + 0x7FFFu + ((u >> 16) & 1u)) >> 16);
}

// async global->LDS, 16B per lane. LDS dest = wave-uniform base + lane*16.
__device__ __forceinline__ void gload_lds16(const void* g, void* l) {
    __builtin_amdgcn_global_load_lds(
        (const __attribute__((address_space(1))) void*)g,
        (__attribute__((address_space(3))) void*)l, 16, 0, 0);
}

__device__ __forceinline__ u16 sgn_bf16(float v) {
    return v > 0.f ? 0x3F80 : (v < 0.f ? 0xBF80 : 0);
}

// --- Prep 1 (fast path): per-row alpha = mean(|W|) AND bit-packed signs,
// TRANSPOSED layout: Wbits[kword][row] -> one K-tile's bits for 256 rows are
// a contiguous 2KB burst. Bitmap = 2MB, L2-resident (r4: FETCH 1.16GB->102MB).
__global__ void prep_wbits_kernel(const float* __restrict__ W,
                                  float* __restrict__ alpha,
                                  u64* __restrict__ Wbits) {
    const int row = blockIdx.x;                       // 0..OUT_F-1
    const int wave = threadIdx.x >> 6, lane = threadIdx.x & 63;
    const float* wr = W + (size_t)row * IN_F;
    float s = 0.f;
#pragma unroll 4
    for (int it = 0; it < 16; ++it) {
        const int kword = it * 4 + wave;              // 64 words per row
        float v = __builtin_nontemporal_load(wr + kword * 64 + lane);
        s += fabsf(v);
        u64 m = __ballot(v > 0.f);                    // 64-bit wave mask
        if (lane == 0) Wbits[(size_t)kword * OUT_F + row] = m;   // transposed
    }
    for (int off = 32; off > 0; off >>= 1) s += __shfl_down(s, off);
    __shared__ float red[4];
    if (lane == 0) red[wave] = s;
    __syncthreads();
    if (threadIdx.x == 0)
        alpha[row] = (red[0] + red[1] + red[2] + red[3]) * (1.0f / IN_F);
}

// --- Prep 2: x fp32 -> bf16 (RNE), chunk-swizzled for T2 (c8 ^= row&7) ---
__global__ void convx_kernel(const float* __restrict__ X, u16* __restrict__ O,
                             int swz) {
    const size_t idx = (size_t)blockIdx.x * 256 + threadIdx.x; // 16B out chunk
    const int row = (int)(idx >> 9);                 // 512 chunks per row
    const int q = (int)idx & 511;
    const int g = q >> 3, c8 = q & 7;
    const int c8s = swz ? (c8 ^ (row & 7)) : c8;
    const f32x4* src = reinterpret_cast<const f32x4*>(
        X + (size_t)row * IN_F + g * 64 + c8s * 8);
    f32x4 a = __builtin_nontemporal_load(src);
    f32x4 b = __builtin_nontemporal_load(src + 1);
    u16x8 r;
    r[0] = f2bf(a[0]); r[1] = f2bf(a[1]); r[2] = f2bf(a[2]); r[3] = f2bf(a[3]);
    r[4] = f2bf(b[0]); r[5] = f2bf(b[1]); r[6] = f2bf(b[2]); r[7] = f2bf(b[3]);
    reinterpret_cast<u16x8*>(O)[idx] = r;
}

// ============================================================================
// 256x256 GEMM, bit-B round 9: BARRIER-STRIPPED (one barrier per K-tile).
// r8 post-mortem: 5380 cyc/tile measured == MFMA (2480) + LDS pipe (~2900)
// run SERIALLY -- the 7 intra-tile barriers lockstep all 8 waves into the
// same phase window, so the LDS-read burst and the MFMA cluster never
// overlap across waves. With A triple-buffered and B double-buffered there
// is NO intra-tile read/write hazard (tile-t reads pa0 & Blds[t&1]; tile-t
// writers touch pa2 & Blds[(t+1)&1]); only the tile boundary needs sync.
// Change: ONE boundary {VM4/VM0 + LGKM0 + BAR} per tile. Waves desync within
// a tile -> one wave's ds_reads overlap another's MFMAs (m114 implicit
// overlap); ds_read->MFMA waits left to the compiler's fine-grained lgkmcnt;
// setprio(1) around MFMA clusters arbitrates (T5 now has role diversity).
// Hazard audit (all separated by >=1 boundary barrier):
//  - stageA(t+2)@t writes the buffer holding A(t-1): last read in tile t-1.
//  - expandB(t+1)@t writes Blds[(t+1)&1] holding B(t-1): last read t-1.
//  - expansion ds_writes drained by own-wave LGKM0 + BAR before t+1 reads.
//  - A(t+1) gload_lds drained by counted VM4 (ledger identical to r8:
//    boundary outstanding = [A(t+1)x4, bits(t+2), A(t+2)x4] = 9 -> VM4
//    leaves A(t+2)x4; tail t>=NT-2 -> VM0).
// ============================================================================
__global__ __launch_bounds__(512, 2) void gemm8_kernel(
    const u16* __restrict__ Xbf, const u64* __restrict__ Wbits,
    const float* __restrict__ alpha, const float* __restrict__ bias,
    float* __restrict__ Y) {
    __shared__ u16 Alds[3][16384];   // 96KB: A triple buffer [256 rows][64 k]
    __shared__ u16 Blds[2][16384];   // 64KB: B double buffer

    const int tid  = threadIdx.x;
    const int lane = tid & 63, wave = tid >> 6;
    const int wm = wave >> 2, wn = wave & 3;      // 2(M) x 4(N) waves
    const int lrow = lane & 15;

    const int wg = blockIdx.x;
    const int i  = wg >> 3;                       // 0..127 within XCD
    const int m0 = (((wg & 7) << 3) | (i >> 4)) << 8;   // xcd*8 + m_local
    const int n0 = (i & 15) << 8;

    // T2 swizzled ds_read k-offsets (u16 units)
    const int q0 = ((lane >> 4) << 3) ^ ((lrow & 7) << 3);
    const int q1 = q0 ^ 32;

    // B-expansion assignment: thread owns 32 bits = row erow, k-half ehalf
    const int erow = tid >> 1, ehalf = tid & 1;
    const u32* Wb32 = reinterpret_cast<const u32*>(Wbits);

    f32x4 acc[8][4];
#pragma unroll
    for (int a = 0; a < 8; ++a)
#pragma unroll
        for (int b = 0; b < 4; ++b) acc[a][b] = (f32x4){0.f, 0.f, 0.f, 0.f};

    // stage one 128-row half of A K-tile th (2 gload_lds16 / thread)
    auto stageA = [&](int th, int half, u16* buf) {
        if (th >= NT) return;
#pragma unroll
        for (int t2 = 0; t2 < 2; ++t2) {
            const int c = half * 1024 + t2 * 512 + tid;   // 16B chunk idx
            const int row = c >> 3, c8 = c & 7;
            gload_lds16(Xbf + (size_t)(m0 + row) * IN_F + th * 64 + c8 * 8,
                        buf + c * 8);
        }
    };

    // expand 2 of this thread's 4 chunks (j = jlo, jlo+1) into Blds[dstbuf].
    // bit=1 -> +1 (0x3F80), bit=0 -> -1 (0xBF80); T2 store swizzle k8^(row&7).
    auto expandB = [&](unsigned b, int dstbuf, int jlo) {
        unsigned nb = ~b;
        u16* base = &Blds[dstbuf][erow * 64];
#pragma unroll
        for (int j = 0; j < 2; ++j) {
            const int jj = jlo + j;
            const int k8 = 4 * ehalf + jj;
            union { unsigned u[4]; u16x8 v; } r;
#pragma unroll
            for (int e = 0; e < 4; ++e) {
                unsigned s = nb >> (jj * 8 + 2 * e);
                r.u[e] = 0x3F803F80u | ((s & 1u) << 15) | ((s & 2u) << 30);
            }
            *reinterpret_cast<u16x8*>(base + ((k8 ^ (erow & 7)) << 3)) = r.v;
        }
    };

    // rotating A-buffer pointers: pa0 = A(t), pa1 = A(t+1), pa2 = stage target
    u16* pa0 = &Alds[0][0];
    u16* pa1 = &Alds[1][0];
    u16* pa2 = &Alds[2][0];

    // ---- prologue ----
    unsigned b0 = Wb32[(size_t)(n0 + erow) * 2 + ehalf];              // bits(0)
    stageA(0, 0, pa0); stageA(0, 1, pa0);
    unsigned bits_cur = Wb32[(size_t)8192 + (n0 + erow) * 2 + ehalf]; // bits(1)
    stageA(1, 0, pa1); stageA(1, 1, pa1);
    unsigned bits_nxt = 0;
    expandB(b0, 0, 0); expandB(b0, 0, 2);   // b0 use forces its drain first
    VM4();   // remaining queue -> leaves A(1)x4 in flight, A(0) complete
    LGKM0(); BAR();

    for (int t = 0; t < NT; ++t) {
        const u16* Ar = pa0 + wm * 8192 + lrow * 64;
        const u16* Br = &Blds[t & 1][0] + wn * 4096 + lrow * 64;
        bf16x8 a0[4][2], a1[4][2], bfr[4][2];

        // ---- issue all frag reads (compiler inserts fine-grained lgkm) ----
#pragma unroll
        for (int mm = 0; mm < 4; ++mm) {
            a0[mm][0] = *reinterpret_cast<const bf16x8*>(Ar + mm * 1024 + q0);
            a0[mm][1] = *reinterpret_cast<const bf16x8*>(Ar + mm * 1024 + q1);
        }
#pragma unroll
        for (int nf = 0; nf < 4; ++nf) {
            bfr[nf][0] = *reinterpret_cast<const bf16x8*>(Br + nf * 1024 + q0);
            bfr[nf][1] = *reinterpret_cast<const bf16x8*>(Br + nf * 1024 + q1);
        }
#pragma unroll
        for (int mm = 0; mm < 4; ++mm) {
            a1[mm][0] = *reinterpret_cast<const bf16x8*>(Ar + (4 + mm) * 1024 + q0);
            a1[mm][1] = *reinterpret_cast<const bf16x8*>(Ar + (4 + mm) * 1024 + q1);
        }
        if (t + 2 < NT)
            bits_nxt = Wb32[(size_t)(t + 2) * 8192 + (n0 + erow) * 2 + ehalf];

        // ---- MFMA cluster 1: mh0 x all np (32 MFMAs) ----
        __builtin_amdgcn_s_setprio(1);
#pragma unroll
        for (int mm = 0; mm < 4; ++mm)
#pragma unroll
            for (int nn = 0; nn < 4; ++nn) {
                acc[mm][nn] = __builtin_amdgcn_mfma_f32_16x16x32_bf16(a0[mm][0], bfr[nn][0], acc[mm][nn], 0, 0, 0);
                acc[mm][nn] = __builtin_amdgcn_mfma_f32_16x16x32_bf16(a0[mm][1], bfr[nn][1], acc[mm][nn], 0, 0, 0);
            }
        __builtin_amdgcn_s_setprio(0);

        // ---- prefetch + expansion (other waves' MFMAs cover these pipes) ----
        stageA(t + 2, 0, pa2);
        stageA(t + 2, 1, pa2);
        if (t + 1 < NT) {
            expandB(bits_cur, (t + 1) & 1, 0);
            expandB(bits_cur, (t + 1) & 1, 2);
        }

        // ---- MFMA cluster 2: mh1 x all np (32 MFMAs) ----
        __builtin_amdgcn_s_setprio(1);
#pragma unroll
        for (int mm = 0; mm < 4; ++mm)
#pragma unroll
            for (int nn = 0; nn < 4; ++nn) {
                acc[4 + mm][nn] = __builtin_amdgcn_mfma_f32_16x16x32_bf16(a1[mm][0], bfr[nn][0], acc[4 + mm][nn], 0, 0, 0);
                acc[4 + mm][nn] = __builtin_amdgcn_mfma_f32_16x16x32_bf16(a1[mm][1], bfr[nn][1], acc[4 + mm][nn], 0, 0, 0);
            }
        __builtin_amdgcn_s_setprio(0);

        // ---- single boundary per tile ----
        if (t >= NT - 2) { VM0(); } else { VM4(); }
        LGKM0(); BAR();

        bits_cur = bits_nxt;
        u16* tp = pa0; pa0 = pa1; pa1 = pa2; pa2 = tp;
    }

    // epilogue: y = acc*alpha[col] + bias[col]; C/D: col=lane&15, row=(lane>>4)*4+r
#pragma unroll
    for (int nf = 0; nf < 4; ++nf) {
        const int col = n0 + wn * 64 + nf * 16 + lrow;
        const float al = alpha[col], bi = bias[col];
#pragma unroll
        for (int mf = 0; mf < 8; ++mf) {
            const int rbase = m0 + wm * 128 + mf * 16 + ((lane >> 4) << 2);
#pragma unroll
            for (int r = 0; r < 4; ++r)
                __builtin_nontemporal_store(acc[mf][nf][r] * al + bi,
                    &Y[(size_t)(rbase + r) * OUT_F + col]);
        }
    }
}

// ============================================================================
// Fallback (small workspace): round-1 128x128 kernel, A reg-staged from fp32,
// bf16 Wsign unswizzled. Verified correct in round 1.
// ============================================================================
__global__ void prep_w_kernel(const float* __restrict__ W,
                              float* __restrict__ alpha,
                              u16* __restrict__ S) {
    const int row = blockIdx.x;
    const float* wr = W + (size_t)row * IN_F;
    float s = 0.f;
    for (int c = threadIdx.x; c < 512; c += 256) {
        const f32x4* src = reinterpret_cast<const f32x4*>(wr + c * 8);
        f32x4 v0 = __builtin_nontemporal_load(src);
        f32x4 v1 = __builtin_nontemporal_load(src + 1);
        s += fabsf(v0[0]) + fabsf(v0[1]) + fabsf(v0[2]) + fabsf(v0[3])
           + fabsf(v1[0]) + fabsf(v1[1]) + fabsf(v1[2]) + fabsf(v1[3]);
        u16x8 r;
        r[0] = sgn_bf16(v0[0]); r[1] = sgn_bf16(v0[1]);
        r[2] = sgn_bf16(v0[2]); r[3] = sgn_bf16(v0[3]);
        r[4] = sgn_bf16(v1[0]); r[5] = sgn_bf16(v1[1]);
        r[6] = sgn_bf16(v1[2]); r[7] = sgn_bf16(v1[3]);
        *reinterpret_cast<u16x8*>(S + (size_t)row * IN_F + c * 8) = r;
    }
    for (int off = 32; off > 0; off >>= 1) s += __shfl_down(s, off);
    __shared__ float red[4];
    const int wave = threadIdx.x >> 6, lane = threadIdx.x & 63;
    if (lane == 0) red[wave] = s;
    __syncthreads();
    if (threadIdx.x == 0)
        alpha[row] = (red[0] + red[1] + red[2] + red[3]) * (1.0f / IN_F);
}

__global__ __launch_bounds__(256) void gemm_fallback(
    const float* __restrict__ X, const u16* __restrict__ Wsign,
    const float* __restrict__ alpha, const float* __restrict__ bias,
    float* __restrict__ Y) {
    __shared__ u16 Axl[128 * 64];
    __shared__ u16 Bxl[128 * 64];

    const int tid = threadIdx.x;
    const int n0 = blockIdx.x * 128;
    const int m0 = blockIdx.y * 128;
    const int wave = tid >> 6, lane = tid & 63;
    const int wm = wave >> 1, wn = wave & 1;
    const int lrow = lane & 15;
    const int lk8 = (lane >> 4) * 8;

    f32x4 acc[4][4];
#pragma unroll
    for (int a = 0; a < 4; ++a)
#pragma unroll
        for (int b = 0; b < 4; ++b) acc[a][b] = (f32x4){0.f, 0.f, 0.f, 0.f};

    for (int kt = 0; kt < IN_F; kt += 64) {
#pragma unroll
        for (int j = 0; j < 4; ++j) {
            const int idx = j * 256 + tid;
            const int row = idx >> 3, c8 = idx & 7;
            gload_lds16(Wsign + (size_t)(n0 + row) * IN_F + kt + c8 * 8,
                        &Bxl[idx * 8]);
        }
#pragma unroll
        for (int j = 0; j < 4; ++j) {
            const int idx = j * 256 + tid;
            const int row = idx >> 3, c8 = idx & 7;
            const float* src = X + (size_t)(m0 + row) * IN_F + kt + c8 * 8;
            float4 v0 = *reinterpret_cast<const float4*>(src);
            float4 v1 = *reinterpret_cast<const float4*>(src + 4);
            u16x8 r;
            r[0] = f2bf(v0.x); r[1] = f2bf(v0.y); r[2] = f2bf(v0.z); r[3] = f2bf(v0.w);
            r[4] = f2bf(v1.x); r[5] = f2bf(v1.y); r[6] = f2bf(v1.z); r[7] = f2bf(v1.w);
            *reinterpret_cast<u16x8*>(&Axl[idx * 8]) = r;
        }
        __syncthreads();
#pragma unroll
        for (int kk = 0; kk < 2; ++kk) {
            bf16x8 af[4], bfv[4];
#pragma unroll
            for (int mf = 0; mf < 4; ++mf)
                af[mf] = *reinterpret_cast<const bf16x8*>(
                    &Axl[(wm * 64 + mf * 16 + lrow) * 64 + kk * 32 + lk8]);
#pragma unroll
            for (int nf = 0; nf < 4; ++nf)
                bfv[nf] = *reinterpret_cast<const bf16x8*>(
                    &Bxl[(wn * 64 + nf * 16 + lrow) * 64 + kk * 32 + lk8]);
#pragma unroll
            for (int mf = 0; mf < 4; ++mf)
#pragma unroll
                for (int nf = 0; nf < 4; ++nf)
                    acc[mf][nf] = __builtin_amdgcn_mfma_f32_16x16x32_bf16(
                        af[mf], bfv[nf], acc[mf][nf], 0, 0, 0);
        }
        __syncthreads();
    }
#pragma unroll
    for (int nf = 0; nf < 4; ++nf) {
        const int col = n0 + wn * 64 + nf * 16 + lrow;
        const float al = alpha[col], bi = bias[col];
#pragma unroll
        for (int mf = 0; mf < 4; ++mf) {
            const int rbase = m0 + wm * 64 + mf * 16 + (lane >> 4) * 4;
#pragma unroll
            for (int r = 0; r < 4; ++r)
                __builtin_nontemporal_store(acc[mf][nf][r] * al + bi,
                    &Y[(size_t)(rbase + r) * OUT_F + col]);
        }
    }
}

extern "C" void kernel_launch(void* const* d_in, const int* in_sizes, int n_in,
                              void* d_out, int out_size, void* d_ws, size_t ws_size,
                              hipStream_t stream) {
    const float* X    = (const float*)d_in[0];
    const float* W    = (const float*)d_in[1];
    const float* bias = (const float*)d_in[2];
    float* Y = (float*)d_out;

    char* ws = (char*)d_ws;
    float* alpha = (float*)ws;                               // 16 KB
    const size_t WBITS_OFF = 16384;
    const size_t XBF_OFF   = WBITS_OFF + (size_t)OUT_F * (IN_F / 8); // +2 MB
    const size_t need_fast = XBF_OFF + (size_t)NROWS * IN_F * 2;     // +128 MB

    if (ws_size >= need_fast) {
        u64* Wbits = (u64*)(ws + WBITS_OFF);
        u16* Xbf   = (u16*)(ws + XBF_OFF);
        prep_wbits_kernel<<<OUT_F, 256, 0, stream>>>(W, alpha, Wbits);
        convx_kernel<<<(size_t)NROWS * IN_F / 8 / 256, 256, 0, stream>>>(X, Xbf, 1);
        gemm8_kernel<<<dim3(1024), 512, 0, stream>>>(Xbf, Wbits, alpha, bias, Y);
    } else {
        u16* Wsign = (u16*)(ws + 16384);
        prep_w_kernel<<<OUT_F, 256, 0, stream>>>(W, alpha, Wsign);
        dim3 grid(OUT_F / 128, NROWS / 128);
        gemm_fallback<<<grid, 256, 0, stream>>>(X, Wsign, alpha, bias, Y);
    }
}

// Round 10
// 514.325 us; speedup vs baseline: 1.1732x; 1.0179x over previous
//
#include <hip/hip_runtime.h>
#include <hip/hip_bf16.h>
#include <stdint.h>

// Problem sizes (fixed by the reference)
#define IN_F  4096
#define OUT_F 4096
#define NROWS 16384
#define NT    (IN_F / 64)   // 64 K-tiles of BK=64

typedef unsigned short u16;
typedef unsigned int u32;
typedef unsigned long long u64;
typedef __bf16 bf16x8 __attribute__((ext_vector_type(8)));
typedef float  f32x4  __attribute__((ext_vector_type(4)));
typedef u16    u16x8  __attribute__((ext_vector_type(8)));

#define BAR()   asm volatile("s_barrier" ::: "memory")
#define LGKM0() asm volatile("s_waitcnt lgkmcnt(0)" ::: "memory")
#define VM4()   asm volatile("s_waitcnt vmcnt(4)" ::: "memory")
#define VM0()   asm volatile("s_waitcnt vmcnt(0)" ::: "memory")

// fp32 -> bf16, round-to-nearest-even (finite inputs only)
__device__ __forceinline__ u16 f2bf(float x) {
    union { float f; uint32_t u; } c; c.f = x;
    uint32_t u = c.u;
    return (u16)((u + 0x7FFFu + ((u >> 16) & 1u)) >> 16);
}

// async global->LDS, 16B per lane. LDS dest = wave-uniform base + lane*16.
__device__ __forceinline__ void gload_lds16(const void* g, void* l) {
    __builtin_amdgcn_global_load_lds(
        (const __attribute__((address_space(1))) void*)g,
        (__attribute__((address_space(3))) void*)l, 16, 0, 0);
}

__device__ __forceinline__ u16 sgn_bf16(float v) {
    return v > 0.f ? 0x3F80 : (v < 0.f ? 0xBF80 : 0);
}

// --- Prep 1 (fast path): per-row alpha = mean(|W|) AND bit-packed signs,
// TRANSPOSED layout: Wbits[kword][row] -> one K-tile's bits for 256 rows are
// a contiguous 2KB burst. Bitmap = 2MB, L2-resident (r4: FETCH 1.16GB->102MB).
__global__ void prep_wbits_kernel(const float* __restrict__ W,
                                  float* __restrict__ alpha,
                                  u64* __restrict__ Wbits) {
    const int row = blockIdx.x;                       // 0..OUT_F-1
    const int wave = threadIdx.x >> 6, lane = threadIdx.x & 63;
    const float* wr = W + (size_t)row * IN_F;
    float s = 0.f;
#pragma unroll 4
    for (int it = 0; it < 16; ++it) {
        const int kword = it * 4 + wave;              // 64 words per row
        float v = __builtin_nontemporal_load(wr + kword * 64 + lane);
        s += fabsf(v);
        u64 m = __ballot(v > 0.f);                    // 64-bit wave mask
        if (lane == 0) Wbits[(size_t)kword * OUT_F + row] = m;   // transposed
    }
    for (int off = 32; off > 0; off >>= 1) s += __shfl_down(s, off);
    __shared__ float red[4];
    if (lane == 0) red[wave] = s;
    __syncthreads();
    if (threadIdx.x == 0)
        alpha[row] = (red[0] + red[1] + red[2] + red[3]) * (1.0f / IN_F);
}

// --- Prep 2: x fp32 -> bf16 (RNE), chunk-swizzled for T2 (c8 ^= row&7) ---
__global__ void convx_kernel(const float* __restrict__ X, u16* __restrict__ O,
                             int swz) {
    const size_t idx = (size_t)blockIdx.x * 256 + threadIdx.x; // 16B out chunk
    const int row = (int)(idx >> 9);                 // 512 chunks per row
    const int q = (int)idx & 511;
    const int g = q >> 3, c8 = q & 7;
    const int c8s = swz ? (c8 ^ (row & 7)) : c8;
    const f32x4* src = reinterpret_cast<const f32x4*>(
        X + (size_t)row * IN_F + g * 64 + c8s * 8);
    f32x4 a = __builtin_nontemporal_load(src);
    f32x4 b = __builtin_nontemporal_load(src + 1);
    u16x8 r;
    r[0] = f2bf(a[0]); r[1] = f2bf(a[1]); r[2] = f2bf(a[2]); r[3] = f2bf(a[3]);
    r[4] = f2bf(b[0]); r[5] = f2bf(b[1]); r[6] = f2bf(b[2]); r[7] = f2bf(b[3]);
    reinterpret_cast<u16x8*>(O)[idx] = r;
}

// ============================================================================
// 256x256 GEMM, bit-B round 10: INTRA-TILE FINE INTERLEAVE.
// r9 verified: 1-barrier/tile, MfmaUtil 49.3%, no spill, FETCH compulsory.
// Remaining gap: tile = 4600 cyc vs max(MFMA 2480, LDS ~2690) -- the boundary
// barrier phase-correlates waves, so each tile begins with a front-loaded
// 24-deep ds_read burst (matrix idle) followed by MFMA clusters (LDS idle).
// Change (compute restructure only): B frags read up front (8 b128), then an
// 8-step ping-pong loop -- step mm prefetches A-frag(mm+1) (2 b128) while
// issuing 8 MFMAs on frag mm. Per step: ~24 cyc LDS vs ~39 cyc matrix, so
// BOTH pipes are fed continuously within one wave's stream (overlap no
// longer relies on wave drift). stageA/expandB spread at fixed mm slots.
// Live A-regs drop 64->16 (no spill risk); full unroll => static indexing.
// Hazards/ledger identical to r9: one boundary {VM4|VM0 + LGKM0 + BAR}/tile;
// A triple-buffered (stageA t+2 -> pa2 holds ex-A(t-1)); B double-buffered
// (expandB t+1 -> Blds[(t+1)&1] holds ex-B(t-1)); boundary outstanding =
// [A(t+1)x4, bits(t+2), A(t+2)x4] = 9 -> VM4 leaves A(t+2)x4; tail VM0.
// ============================================================================
__global__ __launch_bounds__(512, 2) void gemm8_kernel(
    const u16* __restrict__ Xbf, const u64* __restrict__ Wbits,
    const float* __restrict__ alpha, const float* __restrict__ bias,
    float* __restrict__ Y) {
    __shared__ u16 Alds[3][16384];   // 96KB: A triple buffer [256 rows][64 k]
    __shared__ u16 Blds[2][16384];   // 64KB: B double buffer

    const int tid  = threadIdx.x;
    const int lane = tid & 63, wave = tid >> 6;
    const int wm = wave >> 2, wn = wave & 3;      // 2(M) x 4(N) waves
    const int lrow = lane & 15;

    const int wg = blockIdx.x;
    const int i  = wg >> 3;                       // 0..127 within XCD
    const int m0 = (((wg & 7) << 3) | (i >> 4)) << 8;   // xcd*8 + m_local
    const int n0 = (i & 15) << 8;

    // T2 swizzled ds_read k-offsets (u16 units)
    const int q0 = ((lane >> 4) << 3) ^ ((lrow & 7) << 3);
    const int q1 = q0 ^ 32;

    // B-expansion assignment: thread owns 32 bits = row erow, k-half ehalf
    const int erow = tid >> 1, ehalf = tid & 1;
    const u32* Wb32 = reinterpret_cast<const u32*>(Wbits);

    f32x4 acc[8][4];
#pragma unroll
    for (int a = 0; a < 8; ++a)
#pragma unroll
        for (int b = 0; b < 4; ++b) acc[a][b] = (f32x4){0.f, 0.f, 0.f, 0.f};

    // stage one 128-row half of A K-tile th (2 gload_lds16 / thread)
    auto stageA = [&](int th, int half, u16* buf) {
        if (th >= NT) return;
#pragma unroll
        for (int t2 = 0; t2 < 2; ++t2) {
            const int c = half * 1024 + t2 * 512 + tid;   // 16B chunk idx
            const int row = c >> 3, c8 = c & 7;
            gload_lds16(Xbf + (size_t)(m0 + row) * IN_F + th * 64 + c8 * 8,
                        buf + c * 8);
        }
    };

    // expand 2 of this thread's 4 chunks (j = jlo, jlo+1) into Blds[dstbuf].
    // bit=1 -> +1 (0x3F80), bit=0 -> -1 (0xBF80); T2 store swizzle k8^(row&7).
    auto expandB = [&](unsigned b, int dstbuf, int jlo) {
        unsigned nb = ~b;
        u16* base = &Blds[dstbuf][erow * 64];
#pragma unroll
        for (int j = 0; j < 2; ++j) {
            const int jj = jlo + j;
            const int k8 = 4 * ehalf + jj;
            union { unsigned u[4]; u16x8 v; } r;
#pragma unroll
            for (int e = 0; e < 4; ++e) {
                unsigned s = nb >> (jj * 8 + 2 * e);
                r.u[e] = 0x3F803F80u | ((s & 1u) << 15) | ((s & 2u) << 30);
            }
            *reinterpret_cast<u16x8*>(base + ((k8 ^ (erow & 7)) << 3)) = r.v;
        }
    };

    // rotating A-buffer pointers: pa0 = A(t), pa1 = A(t+1), pa2 = stage target
    u16* pa0 = &Alds[0][0];
    u16* pa1 = &Alds[1][0];
    u16* pa2 = &Alds[2][0];

    // ---- prologue ----
    unsigned b0 = Wb32[(size_t)(n0 + erow) * 2 + ehalf];              // bits(0)
    stageA(0, 0, pa0); stageA(0, 1, pa0);
    unsigned bits_cur = Wb32[(size_t)8192 + (n0 + erow) * 2 + ehalf]; // bits(1)
    stageA(1, 0, pa1); stageA(1, 1, pa1);
    unsigned bits_nxt = 0;
    expandB(b0, 0, 0); expandB(b0, 0, 2);   // b0 use forces its drain first
    VM4();   // remaining queue -> leaves A(1)x4 in flight, A(0) complete
    LGKM0(); BAR();

    for (int t = 0; t < NT; ++t) {
        const u16* Ar = pa0 + wm * 8192 + lrow * 64;
        const u16* Br = &Blds[t & 1][0] + wn * 4096 + lrow * 64;
        bf16x8 bfr[4][2];

        // ---- B frags up front (8 b128) ----
#pragma unroll
        for (int nf = 0; nf < 4; ++nf) {
            bfr[nf][0] = *reinterpret_cast<const bf16x8*>(Br + nf * 1024 + q0);
            bfr[nf][1] = *reinterpret_cast<const bf16x8*>(Br + nf * 1024 + q1);
        }
        if (t + 2 < NT)
            bits_nxt = Wb32[(size_t)(t + 2) * 8192 + (n0 + erow) * 2 + ehalf];

        // ---- 8-step ping-pong: prefetch A(mm+1) while MFMA'ing A(mm) ----
        bf16x8 aP0 = *reinterpret_cast<const bf16x8*>(Ar + q0);
        bf16x8 aP1 = *reinterpret_cast<const bf16x8*>(Ar + q1);
#pragma unroll
        for (int mm = 0; mm < 8; ++mm) {
            bf16x8 aQ0, aQ1;
            if (mm < 7) {
                aQ0 = *reinterpret_cast<const bf16x8*>(Ar + (mm + 1) * 1024 + q0);
                aQ1 = *reinterpret_cast<const bf16x8*>(Ar + (mm + 1) * 1024 + q1);
            }
            // spread staging/expansion across the tile (write pipe + VALU
            // issue under the matrix pipe; positions fixed, wave-uniform)
            if (mm == 1) stageA(t + 2, 0, pa2);
            if (mm == 3 && t + 1 < NT) expandB(bits_cur, (t + 1) & 1, 0);
            if (mm == 4) stageA(t + 2, 1, pa2);
            if (mm == 5 && t + 1 < NT) expandB(bits_cur, (t + 1) & 1, 2);

            __builtin_amdgcn_s_setprio(1);
#pragma unroll
            for (int nn = 0; nn < 4; ++nn) {
                acc[mm][nn] = __builtin_amdgcn_mfma_f32_16x16x32_bf16(aP0, bfr[nn][0], acc[mm][nn], 0, 0, 0);
                acc[mm][nn] = __builtin_amdgcn_mfma_f32_16x16x32_bf16(aP1, bfr[nn][1], acc[mm][nn], 0, 0, 0);
            }
            __builtin_amdgcn_s_setprio(0);
            aP0 = aQ0; aP1 = aQ1;
        }

        // ---- single boundary per tile ----
        if (t >= NT - 2) { VM0(); } else { VM4(); }
        LGKM0(); BAR();

        bits_cur = bits_nxt;
        u16* tp = pa0; pa0 = pa1; pa1 = pa2; pa2 = tp;
    }

    // epilogue: y = acc*alpha[col] + bias[col]; C/D: col=lane&15, row=(lane>>4)*4+r
    // acc index mm: mm 0..3 = mh0 rows (wm*128 + mm*16), mm 4..7 = mh1
#pragma unroll
    for (int nf = 0; nf < 4; ++nf) {
        const int col = n0 + wn * 64 + nf * 16 + lrow;
        const float al = alpha[col], bi = bias[col];
#pragma unroll
        for (int mf = 0; mf < 8; ++mf) {
            const int rbase = m0 + wm * 128 + mf * 16 + ((lane >> 4) << 2);
#pragma unroll
            for (int r = 0; r < 4; ++r)
                __builtin_nontemporal_store(acc[mf][nf][r] * al + bi,
                    &Y[(size_t)(rbase + r) * OUT_F + col]);
        }
    }
}

// ============================================================================
// Fallback (small workspace): round-1 128x128 kernel, A reg-staged from fp32,
// bf16 Wsign unswizzled. Verified correct in round 1.
// ============================================================================
__global__ void prep_w_kernel(const float* __restrict__ W,
                              float* __restrict__ alpha,
                              u16* __restrict__ S) {
    const int row = blockIdx.x;
    const float* wr = W + (size_t)row * IN_F;
    float s = 0.f;
    for (int c = threadIdx.x; c < 512; c += 256) {
        const f32x4* src = reinterpret_cast<const f32x4*>(wr + c * 8);
        f32x4 v0 = __builtin_nontemporal_load(src);
        f32x4 v1 = __builtin_nontemporal_load(src + 1);
        s += fabsf(v0[0]) + fabsf(v0[1]) + fabsf(v0[2]) + fabsf(v0[3])
           + fabsf(v1[0]) + fabsf(v1[1]) + fabsf(v1[2]) + fabsf(v1[3]);
        u16x8 r;
        r[0] = sgn_bf16(v0[0]); r[1] = sgn_bf16(v0[1]);
        r[2] = sgn_bf16(v0[2]); r[3] = sgn_bf16(v0[3]);
        r[4] = sgn_bf16(v1[0]); r[5] = sgn_bf16(v1[1]);
        r[6] = sgn_bf16(v1[2]); r[7] = sgn_bf16(v1[3]);
        *reinterpret_cast<u16x8*>(S + (size_t)row * IN_F + c * 8) = r;
    }
    for (int off = 32; off > 0; off >>= 1) s += __shfl_down(s, off);
    __shared__ float red[4];
    const int wave = threadIdx.x >> 6, lane = threadIdx.x & 63;
    if (lane == 0) red[wave] = s;
    __syncthreads();
    if (threadIdx.x == 0)
        alpha[row] = (red[0] + red[1] + red[2] + red[3]) * (1.0f / IN_F);
}

__global__ __launch_bounds__(256) void gemm_fallback(
    const float* __restrict__ X, const u16* __restrict__ Wsign,
    const float* __restrict__ alpha, const float* __restrict__ bias,
    float* __restrict__ Y) {
    __shared__ u16 Axl[128 * 64];
    __shared__ u16 Bxl[128 * 64];

    const int tid = threadIdx.x;
    const int n0 = blockIdx.x * 128;
    const int m0 = blockIdx.y * 128;
    const int wave = tid >> 6, lane = tid & 63;
    const int wm = wave >> 1, wn = wave & 1;
    const int lrow = lane & 15;
    const int lk8 = (lane >> 4) * 8;

    f32x4 acc[4][4];
#pragma unroll
    for (int a = 0; a < 4; ++a)
#pragma unroll
        for (int b = 0; b < 4; ++b) acc[a][b] = (f32x4){0.f, 0.f, 0.f, 0.f};

    for (int kt = 0; kt < IN_F; kt += 64) {
#pragma unroll
        for (int j = 0; j < 4; ++j) {
            const int idx = j * 256 + tid;
            const int row = idx >> 3, c8 = idx & 7;
            gload_lds16(Wsign + (size_t)(n0 + row) * IN_F + kt + c8 * 8,
                        &Bxl[idx * 8]);
        }
#pragma unroll
        for (int j = 0; j < 4; ++j) {
            const int idx = j * 256 + tid;
            const int row = idx >> 3, c8 = idx & 7;
            const float* src = X + (size_t)(m0 + row) * IN_F + kt + c8 * 8;
            float4 v0 = *reinterpret_cast<const float4*>(src);
            float4 v1 = *reinterpret_cast<const float4*>(src + 4);
            u16x8 r;
            r[0] = f2bf(v0.x); r[1] = f2bf(v0.y); r[2] = f2bf(v0.z); r[3] = f2bf(v0.w);
            r[4] = f2bf(v1.x); r[5] = f2bf(v1.y); r[6] = f2bf(v1.z); r[7] = f2bf(v1.w);
            *reinterpret_cast<u16x8*>(&Axl[idx * 8]) = r;
        }
        __syncthreads();
#pragma unroll
        for (int kk = 0; kk < 2; ++kk) {
            bf16x8 af[4], bfv[4];
#pragma unroll
            for (int mf = 0; mf < 4; ++mf)
                af[mf] = *reinterpret_cast<const bf16x8*>(
                    &Axl[(wm * 64 + mf * 16 + lrow) * 64 + kk * 32 + lk8]);
#pragma unroll
            for (int nf = 0; nf < 4; ++nf)
                bfv[nf] = *reinterpret_cast<const bf16x8*>(
                    &Bxl[(wn * 64 + nf * 16 + lrow) * 64 + kk * 32 + lk8]);
#pragma unroll
            for (int mf = 0; mf < 4; ++mf)
#pragma unroll
                for (int nf = 0; nf < 4; ++nf)
                    acc[mf][nf] = __builtin_amdgcn_mfma_f32_16x16x32_bf16(
                        af[mf], bfv[nf], acc[mf][nf], 0, 0, 0);
        }
        __syncthreads();
    }
#pragma unroll
    for (int nf = 0; nf < 4; ++nf) {
        const int col = n0 + wn * 64 + nf * 16 + lrow;
        const float al = alpha[col], bi = bias[col];
#pragma unroll
        for (int mf = 0; mf < 4; ++mf) {
            const int rbase = m0 + wm * 64 + mf * 16 + (lane >> 4) * 4;
#pragma unroll
            for (int r = 0; r < 4; ++r)
                __builtin_nontemporal_store(acc[mf][nf][r] * al + bi,
                    &Y[(size_t)(rbase + r) * OUT_F + col]);
        }
    }
}

extern "C" void kernel_launch(void* const* d_in, const int* in_sizes, int n_in,
                              void* d_out, int out_size, void* d_ws, size_t ws_size,
                              hipStream_t stream) {
    const float* X    = (const float*)d_in[0];
    const float* W    = (const float*)d_in[1];
    const float* bias = (const float*)d_in[2];
    float* Y = (float*)d_out;

    char* ws = (char*)d_ws;
    float* alpha = (float*)ws;                               // 16 KB
    const size_t WBITS_OFF = 16384;
    const size_t XBF_OFF   = WBITS_OFF + (size_t)OUT_F * (IN_F / 8); // +2 MB
    const size_t need_fast = XBF_OFF + (size_t)NROWS * IN_F * 2;     // +128 MB

    if (ws_size >= need_fast) {
        u64* Wbits = (u64*)(ws + WBITS_OFF);
        u16* Xbf   = (u16*)(ws + XBF_OFF);
        prep_wbits_kernel<<<OUT_F, 256, 0, stream>>>(W, alpha, Wbits);
        convx_kernel<<<(size_t)NROWS * IN_F / 8 / 256, 256, 0, stream>>>(X, Xbf, 1);
        gemm8_kernel<<<dim3(1024), 512, 0, stream>>>(Xbf, Wbits, alpha, bias, Y);
    } else {
        u16* Wsign = (u16*)(ws + 16384);
        prep_w_kernel<<<OUT_F, 256, 0, stream>>>(W, alpha, Wsign);
        dim3 grid(OUT_F / 128, NROWS / 128);
        gemm_fallback<<<grid, 256, 0, stream>>>(X, Wsign, alpha, bias, Y);
    }
}